// Round 1
// baseline (5773.022 us; speedup 1.0000x reference)
//
#include <hip/hip_runtime.h>
#include <math.h>

// Problem constants (match reference)
#define D_IN 17
#define DH   32      // hidden dim = H*C
#define H    2
#define C    16
#define TDIM 32
#define NCLS 2
#define TABK 2048    // time-encoding table resolution

// LDS weight pack offsets (floats) for node_prep
#define WL_OFF 0        // 32*17
#define BL_OFF 544
#define WQ_OFF 576      // 32*32
#define BQ_OFF 1600
#define WK_OFF 1632
#define BK_OFF 2656
#define WV_OFF 2688
#define BV_OFF 3712
#define WS_OFF 3744
#define BS_OFF 4768
#define WTOT   4800

// ---------------------------------------------------------------------------
// Kernel 1: per-node h1 = relu(x@Wl.T+bl); q/k/v/skip = h1@W*.T+b*; zero s,agg
// ---------------------------------------------------------------------------
__global__ __launch_bounds__(256) void node_prep(
    const float* __restrict__ x,
    const float* __restrict__ Wl, const float* __restrict__ bl,
    const float* __restrict__ Wq, const float* __restrict__ bq,
    const float* __restrict__ Wk, const float* __restrict__ bk,
    const float* __restrict__ Wv, const float* __restrict__ bv,
    const float* __restrict__ Ws, const float* __restrict__ bs,
    float* __restrict__ qn, float* __restrict__ kn,
    float* __restrict__ vn, float* __restrict__ sk,
    float* __restrict__ s, float* __restrict__ agg, int N)
{
    __shared__ float w[WTOT];
    {
        const float* srcs[10] = {Wl, bl, Wq, bq, Wk, bk, Wv, bv, Ws, bs};
        const int   sizes[10] = {544, 32, 1024, 32, 1024, 32, 1024, 32, 1024, 32};
        int off = 0;
        for (int seg = 0; seg < 10; ++seg) {
            const float* p = srcs[seg];
            int sz = sizes[seg];
            for (int i = threadIdx.x; i < sz; i += blockDim.x) w[off + i] = p[i];
            off += sz;
        }
    }
    __syncthreads();

    int n = blockIdx.x * blockDim.x + threadIdx.x;
    if (n >= N) return;

    float xv[D_IN];
#pragma unroll
    for (int j = 0; j < D_IN; ++j) xv[j] = x[(size_t)n * D_IN + j];

    float h1[DH];
#pragma unroll
    for (int i = 0; i < DH; ++i) {
        float acc = w[BL_OFF + i];
#pragma unroll
        for (int j = 0; j < D_IN; ++j) acc += xv[j] * w[WL_OFF + i * D_IN + j];
        h1[i] = fmaxf(acc, 0.0f);
    }

    float outr[DH];
    float4* dst4;

#define MATVEC(WO, BO, DST)                                                  \
    {                                                                        \
        _Pragma("unroll")                                                    \
        for (int i = 0; i < DH; ++i) {                                       \
            float acc = w[(BO) + i];                                         \
            _Pragma("unroll")                                                \
            for (int c = 0; c < 8; ++c) {                                    \
                float4 wv = *(const float4*)&w[(WO) + i * DH + c * 4];       \
                acc += h1[c * 4 + 0] * wv.x + h1[c * 4 + 1] * wv.y           \
                     + h1[c * 4 + 2] * wv.z + h1[c * 4 + 3] * wv.w;          \
            }                                                                \
            outr[i] = acc;                                                   \
        }                                                                    \
        dst4 = (float4*)((DST) + (size_t)n * DH);                            \
        _Pragma("unroll")                                                    \
        for (int c = 0; c < 8; ++c) {                                        \
            float4 o; o.x = outr[c*4+0]; o.y = outr[c*4+1];                  \
            o.z = outr[c*4+2]; o.w = outr[c*4+3];                            \
            dst4[c] = o;                                                     \
        }                                                                    \
    }

    MATVEC(WQ_OFF, BQ_OFF, qn)
    MATVEC(WK_OFF, BK_OFF, kn)
    MATVEC(WV_OFF, BV_OFF, vn)
    MATVEC(WS_OFF, BS_OFF, sk)
#undef MATVEC

    // zero softmax denominators + aggregation buffer
    s[(size_t)n * 2 + 0] = 0.0f;
    s[(size_t)n * 2 + 1] = 0.0f;
    float4 z; z.x = z.y = z.z = z.w = 0.0f;
    float4* ag4 = (float4*)(agg + (size_t)n * DH);
#pragma unroll
    for (int c = 0; c < 8; ++c) ag4[c] = z;
}

// ---------------------------------------------------------------------------
// Kernel 2: time-encoding lookup table  T[k][o] = sum_j We[o,j]*cos(r_k*f_j+ph_j)+be[o]
// r_k = -1 + 2k/TABK,  k in [0, TABK]
// ---------------------------------------------------------------------------
__global__ __launch_bounds__(64) void build_table(
    const float* __restrict__ We, const float* __restrict__ be,
    const float* __restrict__ freq, const float* __restrict__ phase,
    float* __restrict__ table)
{
    int k = blockIdx.x * blockDim.x + threadIdx.x;
    if (k > TABK) return;
    float r = -1.0f + 2.0f * (float)k / (float)TABK;
    float cj[TDIM];
#pragma unroll
    for (int j = 0; j < TDIM; ++j) cj[j] = cosf(r * freq[j] + phase[j]);
#pragma unroll 4
    for (int o = 0; o < DH; ++o) {
        float acc = be[o];
#pragma unroll
        for (int j = 0; j < TDIM; ++j) acc += cj[j] * We[o * TDIM + j];
        table[(size_t)k * DH + o] = acc;
    }
}

// ---------------------------------------------------------------------------
// Kernel 3: single edge pass. alpha=dot(q[dst], k[src]+e)/4, a=exp(alpha),
//           atomic s[dst,h]+=a ; atomic agg[dst,:]+= (v[src]+e)*a
// ---------------------------------------------------------------------------
__global__ __launch_bounds__(256) void edge_pass(
    const int* __restrict__ ei, const float* __restrict__ t,
    const float* __restrict__ ntime,
    const float* __restrict__ qn, const float* __restrict__ kn,
    const float* __restrict__ vn, const float* __restrict__ table,
    float* __restrict__ s, float* __restrict__ agg, int E)
{
    int e = blockIdx.x * blockDim.x + threadIdx.x;
    if (e >= E) return;

    int src = ei[e];
    int dst = ei[E + e];

    float rel = ntime[src] - t[e];
    float u = (rel + 1.0f) * ((float)TABK * 0.5f);
    int i0 = (int)u;
    i0 = min(max(i0, 0), TABK - 1);
    float fr = u - (float)i0;

    // e_vec via lerp of two 32-float table rows
    float ev[DH];
    {
        const float4* t0 = (const float4*)(table + (size_t)i0 * DH);
        const float4* t1 = (const float4*)(table + (size_t)(i0 + 1) * DH);
#pragma unroll
        for (int c = 0; c < 8; ++c) {
            float4 a = t0[c], b = t1[c];
            ev[c * 4 + 0] = a.x + fr * (b.x - a.x);
            ev[c * 4 + 1] = a.y + fr * (b.y - a.y);
            ev[c * 4 + 2] = a.z + fr * (b.z - a.z);
            ev[c * 4 + 3] = a.w + fr * (b.w - a.w);
        }
    }

    // attention logits per head
    float aw[H];
#pragma unroll
    for (int h = 0; h < H; ++h) {
        const float4* q4 = (const float4*)(qn + (size_t)dst * DH + h * C);
        const float4* k4 = (const float4*)(kn + (size_t)src * DH + h * C);
        float acc = 0.0f;
#pragma unroll
        for (int c = 0; c < 4; ++c) {
            float4 q = q4[c];
            float4 k = k4[c];
            int b = h * C + c * 4;
            acc += q.x * (k.x + ev[b + 0]);
            acc += q.y * (k.y + ev[b + 1]);
            acc += q.z * (k.z + ev[b + 2]);
            acc += q.w * (k.w + ev[b + 3]);
        }
        aw[h] = __expf(acc * 0.25f);   // 1/sqrt(C)=0.25; no max needed (|logit| small)
    }

    atomicAdd(&s[(size_t)dst * 2 + 0], aw[0]);
    atomicAdd(&s[(size_t)dst * 2 + 1], aw[1]);

    const float4* v4 = (const float4*)(vn + (size_t)src * DH);
    float* ag = agg + (size_t)dst * DH;
#pragma unroll
    for (int c = 0; c < 8; ++c) {
        float4 v = v4[c];
        float wgt = (c < 4) ? aw[0] : aw[1];
        atomicAdd(&ag[c * 4 + 0], (v.x + ev[c * 4 + 0]) * wgt);
        atomicAdd(&ag[c * 4 + 1], (v.y + ev[c * 4 + 1]) * wgt);
        atomicAdd(&ag[c * 4 + 2], (v.z + ev[c * 4 + 2]) * wgt);
        atomicAdd(&ag[c * 4 + 3], (v.w + ev[c * 4 + 3]) * wgt);
    }
}

// ---------------------------------------------------------------------------
// Kernel 4: h = agg/s + skip ; logits = h@Wout.T+bout ; log_softmax
// ---------------------------------------------------------------------------
__global__ __launch_bounds__(256) void finalize(
    const float* __restrict__ sk, const float* __restrict__ s,
    const float* __restrict__ agg,
    const float* __restrict__ Wout, const float* __restrict__ bout,
    float* __restrict__ out, int N)
{
    int n = blockIdx.x * blockDim.x + threadIdx.x;
    if (n >= N) return;

    float s0 = s[(size_t)n * 2 + 0];
    float s1 = s[(size_t)n * 2 + 1];
    float r0 = (s0 > 0.0f) ? 1.0f / s0 : 0.0f;
    float r1 = (s1 > 0.0f) ? 1.0f / s1 : 0.0f;

    float hv[DH];
    const float4* ag4 = (const float4*)(agg + (size_t)n * DH);
    const float4* sk4 = (const float4*)(sk + (size_t)n * DH);
#pragma unroll
    for (int c = 0; c < 8; ++c) {
        float4 a = ag4[c];
        float4 k = sk4[c];
        float r = (c < 4) ? r0 : r1;
        hv[c * 4 + 0] = a.x * r + k.x;
        hv[c * 4 + 1] = a.y * r + k.y;
        hv[c * 4 + 2] = a.z * r + k.z;
        hv[c * 4 + 3] = a.w * r + k.w;
    }

    float l0 = bout[0], l1 = bout[1];
#pragma unroll
    for (int c = 0; c < DH; ++c) {
        l0 += hv[c] * Wout[c];
        l1 += hv[c] * Wout[DH + c];
    }

    float m = fmaxf(l0, l1);
    float lse = m + logf(__expf(l0 - m) + __expf(l1 - m));
    out[(size_t)n * 2 + 0] = l0 - lse;
    out[(size_t)n * 2 + 1] = l1 - lse;
}

// ---------------------------------------------------------------------------
extern "C" void kernel_launch(void* const* d_in, const int* in_sizes, int n_in,
                              void* d_out, int out_size, void* d_ws, size_t ws_size,
                              hipStream_t stream)
{
    const float* x      = (const float*)d_in[0];
    const int*   ei     = (const int*)d_in[1];
    const float* t      = (const float*)d_in[2];
    const float* ntime  = (const float*)d_in[3];
    const float* freq   = (const float*)d_in[4];
    const float* phase  = (const float*)d_in[5];
    const float* Wl     = (const float*)d_in[6];
    const float* bl     = (const float*)d_in[7];
    const float* Wq     = (const float*)d_in[8];
    const float* bq     = (const float*)d_in[9];
    const float* Wk     = (const float*)d_in[10];
    const float* bk     = (const float*)d_in[11];
    const float* Wv     = (const float*)d_in[12];
    const float* bv     = (const float*)d_in[13];
    const float* We     = (const float*)d_in[14];
    const float* be     = (const float*)d_in[15];
    const float* Ws     = (const float*)d_in[16];
    const float* bs     = (const float*)d_in[17];
    const float* Wout   = (const float*)d_in[18];
    const float* bout   = (const float*)d_in[19];

    const int E = in_sizes[2];        // t has E elements
    const int N = in_sizes[3];        // node_time has N elements

    float* ws   = (float*)d_ws;
    float* qn   = ws;                         // N*32
    float* kn   = qn + (size_t)N * DH;        // N*32
    float* vn   = kn + (size_t)N * DH;        // N*32
    float* skip = vn + (size_t)N * DH;        // N*32
    float* tab  = skip + (size_t)N * DH;      // (TABK+1)*32
    float* s    = tab + (size_t)(TABK + 1) * DH;  // N*2
    float* agg  = s + (size_t)N * 2;          // N*32

    float* out = (float*)d_out;

    int nblk = (N + 255) / 256;
    node_prep<<<nblk, 256, 0, stream>>>(x, Wl, bl, Wq, bq, Wk, bk, Wv, bv, Ws, bs,
                                        qn, kn, vn, skip, s, agg, N);

    build_table<<<(TABK + 64) / 64, 64, 0, stream>>>(We, be, freq, phase, tab);

    int eblk = (E + 255) / 256;
    edge_pass<<<eblk, 256, 0, stream>>>(ei, t, ntime, qn, kn, vn, tab, s, agg, E);

    finalize<<<nblk, 256, 0, stream>>>(skip, s, agg, Wout, bout, out, N);
}

// Round 2
// 542.588 us; speedup vs baseline: 10.6398x; 10.6398x over previous
//
#include <hip/hip_runtime.h>
#include <math.h>

// Problem constants (match reference)
#define D_IN 17
#define DH   32      // hidden dim = H*C
#define H    2
#define C    16
#define TDIM 32
#define NCLS 2
#define TABK 2048    // time-encoding table resolution

// LDS weight pack offsets (floats) for node_prep
#define WL_OFF 0        // 32*17
#define BL_OFF 544
#define WQ_OFF 576      // 32*32
#define BQ_OFF 1600
#define WK_OFF 1632
#define BK_OFF 2656
#define WV_OFF 2688
#define BV_OFF 3712
#define WS_OFF 3744
#define BS_OFF 4768
#define WTOT   4800

#define SCAN_T 256
#define SCAN_I 4
#define SCAN_B (SCAN_T * SCAN_I)   // 1024 items per scan block

// ---------------------------------------------------------------------------
// Kernel 1: per-node h1 = relu(x@Wl.T+bl); q/k/v/skip = h1@W*.T+b*; zero cnt
// ---------------------------------------------------------------------------
__global__ __launch_bounds__(256) void node_prep(
    const float* __restrict__ x,
    const float* __restrict__ Wl, const float* __restrict__ bl,
    const float* __restrict__ Wq, const float* __restrict__ bq,
    const float* __restrict__ Wk, const float* __restrict__ bk,
    const float* __restrict__ Wv, const float* __restrict__ bv,
    const float* __restrict__ Ws, const float* __restrict__ bs,
    float* __restrict__ qn, float* __restrict__ kn,
    float* __restrict__ vn, float* __restrict__ sk,
    int* __restrict__ cnt, int N)
{
    __shared__ float w[WTOT];
    {
        const float* srcs[10] = {Wl, bl, Wq, bq, Wk, bk, Wv, bv, Ws, bs};
        const int   sizes[10] = {544, 32, 1024, 32, 1024, 32, 1024, 32, 1024, 32};
        int off = 0;
        for (int seg = 0; seg < 10; ++seg) {
            const float* p = srcs[seg];
            int sz = sizes[seg];
            for (int i = threadIdx.x; i < sz; i += blockDim.x) w[off + i] = p[i];
            off += sz;
        }
    }
    __syncthreads();

    int n = blockIdx.x * blockDim.x + threadIdx.x;
    if (n >= N) return;

    cnt[n] = 0;

    float xv[D_IN];
#pragma unroll
    for (int j = 0; j < D_IN; ++j) xv[j] = x[(size_t)n * D_IN + j];

    float h1[DH];
#pragma unroll
    for (int i = 0; i < DH; ++i) {
        float acc = w[BL_OFF + i];
#pragma unroll
        for (int j = 0; j < D_IN; ++j) acc += xv[j] * w[WL_OFF + i * D_IN + j];
        h1[i] = fmaxf(acc, 0.0f);
    }

    float outr[DH];
    float4* dst4;

#define MATVEC(WO, BO, DST)                                                  \
    {                                                                        \
        _Pragma("unroll")                                                    \
        for (int i = 0; i < DH; ++i) {                                       \
            float acc = w[(BO) + i];                                         \
            _Pragma("unroll")                                                \
            for (int c = 0; c < 8; ++c) {                                    \
                float4 wv = *(const float4*)&w[(WO) + i * DH + c * 4];       \
                acc += h1[c * 4 + 0] * wv.x + h1[c * 4 + 1] * wv.y           \
                     + h1[c * 4 + 2] * wv.z + h1[c * 4 + 3] * wv.w;          \
            }                                                                \
            outr[i] = acc;                                                   \
        }                                                                    \
        dst4 = (float4*)((DST) + (size_t)n * DH);                            \
        _Pragma("unroll")                                                    \
        for (int c = 0; c < 8; ++c) {                                        \
            float4 o; o.x = outr[c*4+0]; o.y = outr[c*4+1];                  \
            o.z = outr[c*4+2]; o.w = outr[c*4+3];                            \
            dst4[c] = o;                                                     \
        }                                                                    \
    }

    MATVEC(WQ_OFF, BQ_OFF, qn)
    MATVEC(WK_OFF, BK_OFF, kn)
    MATVEC(WV_OFF, BV_OFF, vn)
    MATVEC(WS_OFF, BS_OFF, sk)
#undef MATVEC
}

// ---------------------------------------------------------------------------
// Kernel 2: time-encoding lookup table  T[k][o] = sum_j We[o,j]*cos(r_k*f_j+ph_j)+be[o]
// ---------------------------------------------------------------------------
__global__ __launch_bounds__(64) void build_table(
    const float* __restrict__ We, const float* __restrict__ be,
    const float* __restrict__ freq, const float* __restrict__ phase,
    float* __restrict__ table)
{
    int k = blockIdx.x * blockDim.x + threadIdx.x;
    if (k > TABK) return;
    float r = -1.0f + 2.0f * (float)k / (float)TABK;
    float cj[TDIM];
#pragma unroll
    for (int j = 0; j < TDIM; ++j) cj[j] = cosf(r * freq[j] + phase[j]);
#pragma unroll 4
    for (int o = 0; o < DH; ++o) {
        float acc = be[o];
#pragma unroll
        for (int j = 0; j < TDIM; ++j) acc += cj[j] * We[o * TDIM + j];
        table[(size_t)k * DH + o] = acc;
    }
}

// ---------------------------------------------------------------------------
// Kernel 3: histogram of dst
// ---------------------------------------------------------------------------
__global__ __launch_bounds__(256) void hist_k(
    const int* __restrict__ ei, int* __restrict__ cnt, int E)
{
    int e = blockIdx.x * blockDim.x + threadIdx.x;
    if (e < E) atomicAdd(&cnt[ei[E + e]], 1);
}

// ---------------------------------------------------------------------------
// Scan kernels: exclusive prefix sum over cnt[N] -> off[N], cur[N]=off[N]
// ---------------------------------------------------------------------------
__global__ __launch_bounds__(SCAN_T) void scan_reduce(
    const int* __restrict__ cnt, int* __restrict__ bsum, int N)
{
    __shared__ int sd[SCAN_T];
    int base = blockIdx.x * SCAN_B + threadIdx.x * SCAN_I;
    int s = 0;
#pragma unroll
    for (int k = 0; k < SCAN_I; ++k) { int i = base + k; if (i < N) s += cnt[i]; }
    sd[threadIdx.x] = s;
    __syncthreads();
    for (int st = SCAN_T / 2; st > 0; st >>= 1) {
        if (threadIdx.x < st) sd[threadIdx.x] += sd[threadIdx.x + st];
        __syncthreads();
    }
    if (threadIdx.x == 0) bsum[blockIdx.x] = sd[0];
}

__global__ __launch_bounds__(1024) void scan_bsum(int* __restrict__ bsum, int nb)
{
    __shared__ int sd[1024];
    int t = threadIdx.x;
    int orig = (t < nb) ? bsum[t] : 0;
    sd[t] = orig;
    __syncthreads();
    for (int st = 1; st < 1024; st <<= 1) {
        int v = (t >= st) ? sd[t - st] : 0;
        __syncthreads();
        sd[t] += v;
        __syncthreads();
    }
    if (t < nb) bsum[t] = sd[t] - orig;   // exclusive
}

__global__ __launch_bounds__(SCAN_T) void scan_final(
    const int* __restrict__ cnt, const int* __restrict__ bsum,
    int* __restrict__ off, int* __restrict__ cur, int N)
{
    __shared__ int sd[SCAN_T];
    int t = threadIdx.x;
    int base = blockIdx.x * SCAN_B + t * SCAN_I;
    int loc[SCAN_I];
    int s = 0;
#pragma unroll
    for (int k = 0; k < SCAN_I; ++k) { int i = base + k; loc[k] = (i < N) ? cnt[i] : 0; s += loc[k]; }
    int orig = s;
    sd[t] = s;
    __syncthreads();
    for (int st = 1; st < SCAN_T; st <<= 1) {
        int v = (t >= st) ? sd[t - st] : 0;
        __syncthreads();
        sd[t] += v;
        __syncthreads();
    }
    int ex = sd[t] - orig + bsum[blockIdx.x];
#pragma unroll
    for (int k = 0; k < SCAN_I; ++k) {
        int i = base + k;
        if (i < N) { off[i] = ex; cur[i] = ex; ex += loc[k]; }
    }
}

// ---------------------------------------------------------------------------
// Kernel 4: scatter edges into dst buckets. payload = {src, rel_t bits}
// ---------------------------------------------------------------------------
__global__ __launch_bounds__(256) void scatter_k(
    const int* __restrict__ ei, const float* __restrict__ t,
    const float* __restrict__ ntime,
    int* __restrict__ cur, int2* __restrict__ payload, int E)
{
    int e = blockIdx.x * blockDim.x + threadIdx.x;
    if (e >= E) return;
    int src = ei[e];
    int dst = ei[E + e];
    float rel = ntime[src] - t[e];
    int pos = atomicAdd(&cur[dst], 1);
    payload[pos] = make_int2(src, __float_as_int(rel));
}

// ---------------------------------------------------------------------------
// Kernel 5: gather + finalize. 8 lanes per dst node, no atomics.
// ---------------------------------------------------------------------------
__global__ __launch_bounds__(256) void gather_pass(
    const int* __restrict__ off, const int* __restrict__ cnt,
    const int2* __restrict__ payload,
    const float* __restrict__ qn, const float* __restrict__ kn,
    const float* __restrict__ vn, const float* __restrict__ skipv,
    const float* __restrict__ table,
    const float* __restrict__ Wout, const float* __restrict__ bout,
    float* __restrict__ out, int N)
{
    int tid = blockIdx.x * blockDim.x + threadIdx.x;
    int d = tid >> 3;          // 8 lanes per dst
    int sub = tid & 7;         // channel group: 4 floats each
    if (d >= N) return;

    const float4 q = *(const float4*)(qn + (size_t)d * DH + sub * 4);
    float4 acc; acc.x = acc.y = acc.z = acc.w = 0.0f;
    float ssum = 0.0f;

    int beg = off[d];
    int num = cnt[d];
    for (int j = 0; j < num; ++j) {
        int2 pl = payload[beg + j];
        int src = pl.x;
        float rel = __int_as_float(pl.y);
        float u = (rel + 1.0f) * ((float)TABK * 0.5f);
        int i0 = (int)u;
        i0 = min(max(i0, 0), TABK - 1);
        float fr = u - (float)i0;

        const float4 t0 = *(const float4*)(table + (size_t)i0 * DH + sub * 4);
        const float4 t1 = *(const float4*)(table + (size_t)(i0 + 1) * DH + sub * 4);
        float4 ev;
        ev.x = t0.x + fr * (t1.x - t0.x);
        ev.y = t0.y + fr * (t1.y - t0.y);
        ev.z = t0.z + fr * (t1.z - t0.z);
        ev.w = t0.w + fr * (t1.w - t0.w);

        const float4 k = *(const float4*)(kn + (size_t)src * DH + sub * 4);
        float part = q.x * (k.x + ev.x) + q.y * (k.y + ev.y)
                   + q.z * (k.z + ev.z) + q.w * (k.w + ev.w);
        // per-head reduce: head = sub/4, lanes {sub&~3 .. sub|3}
        part += __shfl_xor(part, 1);
        part += __shfl_xor(part, 2);
        float wgt = __expf(part * 0.25f);   // 1/sqrt(C)=0.25; logits tiny, no max needed
        ssum += wgt;

        const float4 v = *(const float4*)(vn + (size_t)src * DH + sub * 4);
        acc.x += (v.x + ev.x) * wgt;
        acc.y += (v.y + ev.y) * wgt;
        acc.z += (v.z + ev.z) * wgt;
        acc.w += (v.w + ev.w) * wgt;
    }

    float r = (ssum > 0.0f) ? 1.0f / ssum : 0.0f;
    const float4 sk = *(const float4*)(skipv + (size_t)d * DH + sub * 4);
    float4 h;
    h.x = acc.x * r + sk.x;
    h.y = acc.y * r + sk.y;
    h.z = acc.z * r + sk.z;
    h.w = acc.w * r + sk.w;

    const float4 w0 = *(const float4*)(Wout + sub * 4);
    const float4 w1 = *(const float4*)(Wout + DH + sub * 4);
    float l0 = h.x * w0.x + h.y * w0.y + h.z * w0.z + h.w * w0.w;
    float l1 = h.x * w1.x + h.y * w1.y + h.z * w1.z + h.w * w1.w;
    l0 += __shfl_xor(l0, 1); l0 += __shfl_xor(l0, 2); l0 += __shfl_xor(l0, 4);
    l1 += __shfl_xor(l1, 1); l1 += __shfl_xor(l1, 2); l1 += __shfl_xor(l1, 4);

    if (sub == 0) {
        l0 += bout[0];
        l1 += bout[1];
        float m = fmaxf(l0, l1);
        float lse = m + logf(__expf(l0 - m) + __expf(l1 - m));
        float2 o; o.x = l0 - lse; o.y = l1 - lse;
        *(float2*)(out + (size_t)d * 2) = o;
    }
}

// ---------------------------------------------------------------------------
extern "C" void kernel_launch(void* const* d_in, const int* in_sizes, int n_in,
                              void* d_out, int out_size, void* d_ws, size_t ws_size,
                              hipStream_t stream)
{
    const float* x      = (const float*)d_in[0];
    const int*   ei     = (const int*)d_in[1];
    const float* t      = (const float*)d_in[2];
    const float* ntime  = (const float*)d_in[3];
    const float* freq   = (const float*)d_in[4];
    const float* phase  = (const float*)d_in[5];
    const float* Wl     = (const float*)d_in[6];
    const float* bl     = (const float*)d_in[7];
    const float* Wq     = (const float*)d_in[8];
    const float* bq     = (const float*)d_in[9];
    const float* Wk     = (const float*)d_in[10];
    const float* bk     = (const float*)d_in[11];
    const float* Wv     = (const float*)d_in[12];
    const float* bv     = (const float*)d_in[13];
    const float* We     = (const float*)d_in[14];
    const float* be     = (const float*)d_in[15];
    const float* Ws     = (const float*)d_in[16];
    const float* bs     = (const float*)d_in[17];
    const float* Wout   = (const float*)d_in[18];
    const float* bout   = (const float*)d_in[19];

    const int E = in_sizes[2];        // t has E elements
    const int N = in_sizes[3];        // node_time has N elements

    char* wsb = (char*)d_ws;
    int2*  payload = (int2*)wsb;                       wsb += (size_t)E * sizeof(int2);
    float* qn   = (float*)wsb;                         wsb += (size_t)N * DH * 4;
    float* kn   = (float*)wsb;                         wsb += (size_t)N * DH * 4;
    float* vn   = (float*)wsb;                         wsb += (size_t)N * DH * 4;
    float* skip = (float*)wsb;                         wsb += (size_t)N * DH * 4;
    float* tab  = (float*)wsb;                         wsb += (size_t)(TABK + 1) * DH * 4;
    int*   cnt  = (int*)wsb;                           wsb += (size_t)N * 4;
    int*   off  = (int*)wsb;                           wsb += (size_t)N * 4;
    int*   cur  = (int*)wsb;                           wsb += (size_t)N * 4;
    int*   bsum = (int*)wsb;                           wsb += 1024 * 4;

    float* out = (float*)d_out;

    int nblk = (N + 255) / 256;
    int eblk = (E + 255) / 256;
    int sblk = (N + SCAN_B - 1) / SCAN_B;   // scan blocks (<=1024)

    node_prep<<<nblk, 256, 0, stream>>>(x, Wl, bl, Wq, bq, Wk, bk, Wv, bv, Ws, bs,
                                        qn, kn, vn, skip, cnt, N);
    build_table<<<(TABK + 64) / 64, 64, 0, stream>>>(We, be, freq, phase, tab);
    hist_k<<<eblk, 256, 0, stream>>>(ei, cnt, E);
    scan_reduce<<<sblk, SCAN_T, 0, stream>>>(cnt, bsum, N);
    scan_bsum<<<1, 1024, 0, stream>>>(bsum, sblk);
    scan_final<<<sblk, SCAN_T, 0, stream>>>(cnt, bsum, off, cur, N);
    scatter_k<<<eblk, 256, 0, stream>>>(ei, t, ntime, cur, payload, E);

    int gblk = ((size_t)N * 8 + 255) / 256;
    gather_pass<<<gblk, 256, 0, stream>>>(off, cnt, payload, qn, kn, vn, skip,
                                          tab, Wout, bout, out, N);
}

// Round 3
// 412.296 us; speedup vs baseline: 14.0021x; 1.3160x over previous
//
#include <hip/hip_runtime.h>
#include <math.h>

// Problem constants (match reference)
#define D_IN 17
#define DH   32      // hidden dim = H*C
#define H    2
#define C    16
#define TDIM 32
#define TABK 2048    // time-encoding table resolution

#define NBSH 10                  // nodes per coarse bucket = 1024
#define S1_TILE 8192             // edges per s1 block

// LDS weight pack offsets (floats) for node_prep
#define WL_OFF 0        // 32*17
#define BL_OFF 544
#define WQ_OFF 576      // 32*32
#define BQ_OFF 1600
#define WK_OFF 1632
#define BK_OFF 2656
#define WV_OFF 2688
#define BV_OFF 3712
#define WS_OFF 3744
#define BS_OFF 4768
#define WTOT   4800

#define SCAN_T 256
#define SCAN_I 4
#define SCAN_B (SCAN_T * SCAN_I)   // 1024 items per scan block

__device__ __forceinline__ unsigned int f2bf(float x) {
    unsigned int u = __float_as_uint(x);
    return (u + 0x7fffu + ((u >> 16) & 1u)) >> 16;   // RTNE, no NaN expected
}
__device__ __forceinline__ float bfl(unsigned int u) { return __uint_as_float(u << 16); }
__device__ __forceinline__ float bfh(unsigned int u) { return __uint_as_float(u & 0xffff0000u); }

// ---------------------------------------------------------------------------
// Kernel 1: h1 = relu(x@Wl.T+bl); q (f32), k/v packed bf16 (128B/row), skip f32
// ---------------------------------------------------------------------------
__global__ __launch_bounds__(256) void node_prep(
    const float* __restrict__ x,
    const float* __restrict__ Wl, const float* __restrict__ bl,
    const float* __restrict__ Wq, const float* __restrict__ bq,
    const float* __restrict__ Wk, const float* __restrict__ bk,
    const float* __restrict__ Wv, const float* __restrict__ bv,
    const float* __restrict__ Ws, const float* __restrict__ bs,
    float* __restrict__ qn, unsigned short* __restrict__ kvn,
    float* __restrict__ skv, int* __restrict__ cnt, int N)
{
    __shared__ float w[WTOT];
    {
        const float* srcs[10] = {Wl, bl, Wq, bq, Wk, bk, Wv, bv, Ws, bs};
        const int   sizes[10] = {544, 32, 1024, 32, 1024, 32, 1024, 32, 1024, 32};
        int off = 0;
        for (int seg = 0; seg < 10; ++seg) {
            const float* p = srcs[seg];
            int sz = sizes[seg];
            for (int i = threadIdx.x; i < sz; i += blockDim.x) w[off + i] = p[i];
            off += sz;
        }
    }
    __syncthreads();

    int n = blockIdx.x * blockDim.x + threadIdx.x;
    if (n >= N) return;

    cnt[n] = 0;

    float xv[D_IN];
#pragma unroll
    for (int j = 0; j < D_IN; ++j) xv[j] = x[(size_t)n * D_IN + j];

    float h1[DH];
#pragma unroll
    for (int i = 0; i < DH; ++i) {
        float acc = w[BL_OFF + i];
#pragma unroll
        for (int j = 0; j < D_IN; ++j) acc += xv[j] * w[WL_OFF + i * D_IN + j];
        h1[i] = fmaxf(acc, 0.0f);
    }

    float outr[DH];

#define MATVEC(WO, BO)                                                       \
    {                                                                        \
        _Pragma("unroll")                                                    \
        for (int i = 0; i < DH; ++i) {                                       \
            float acc = w[(BO) + i];                                         \
            _Pragma("unroll")                                                \
            for (int c = 0; c < 8; ++c) {                                    \
                float4 wv = *(const float4*)&w[(WO) + i * DH + c * 4];       \
                acc += h1[c * 4 + 0] * wv.x + h1[c * 4 + 1] * wv.y           \
                     + h1[c * 4 + 2] * wv.z + h1[c * 4 + 3] * wv.w;          \
            }                                                                \
            outr[i] = acc;                                                   \
        }                                                                    \
    }

    // q -> f32
    MATVEC(WQ_OFF, BQ_OFF)
    {
        float4* dst4 = (float4*)(qn + (size_t)n * DH);
#pragma unroll
        for (int c = 0; c < 8; ++c) {
            float4 o; o.x = outr[c*4+0]; o.y = outr[c*4+1];
            o.z = outr[c*4+2]; o.w = outr[c*4+3];
            dst4[c] = o;
        }
    }

    // k -> bf16 packed (first 64B of row)
    unsigned int kw[16], vw[16];
    MATVEC(WK_OFF, BK_OFF)
#pragma unroll
    for (int i = 0; i < 16; ++i)
        kw[i] = f2bf(outr[2*i]) | (f2bf(outr[2*i+1]) << 16);

    // v -> bf16 packed (second 64B of row)
    MATVEC(WV_OFF, BV_OFF)
#pragma unroll
    for (int i = 0; i < 16; ++i)
        vw[i] = f2bf(outr[2*i]) | (f2bf(outr[2*i+1]) << 16);

    {
        uint4* row = (uint4*)(kvn + (size_t)n * 64);
#pragma unroll
        for (int c = 0; c < 4; ++c) {
            uint4 o; o.x = kw[c*4+0]; o.y = kw[c*4+1]; o.z = kw[c*4+2]; o.w = kw[c*4+3];
            row[c] = o;
        }
#pragma unroll
        for (int c = 0; c < 4; ++c) {
            uint4 o; o.x = vw[c*4+0]; o.y = vw[c*4+1]; o.z = vw[c*4+2]; o.w = vw[c*4+3];
            row[4 + c] = o;
        }
    }

    // skip -> f32
    MATVEC(WS_OFF, BS_OFF)
    {
        float4* dst4 = (float4*)(skv + (size_t)n * DH);
#pragma unroll
        for (int c = 0; c < 8; ++c) {
            float4 o; o.x = outr[c*4+0]; o.y = outr[c*4+1];
            o.z = outr[c*4+2]; o.w = outr[c*4+3];
            dst4[c] = o;
        }
    }
#undef MATVEC
}

// ---------------------------------------------------------------------------
// Kernel 2: time-encoding lookup table
// ---------------------------------------------------------------------------
__global__ __launch_bounds__(64) void build_table(
    const float* __restrict__ We, const float* __restrict__ be,
    const float* __restrict__ freq, const float* __restrict__ phase,
    float* __restrict__ table)
{
    int k = blockIdx.x * blockDim.x + threadIdx.x;
    if (k > TABK) return;
    float r = -1.0f + 2.0f * (float)k / (float)TABK;
    float cj[TDIM];
#pragma unroll
    for (int j = 0; j < TDIM; ++j) cj[j] = cosf(r * freq[j] + phase[j]);
#pragma unroll 4
    for (int o = 0; o < DH; ++o) {
        float acc = be[o];
#pragma unroll
        for (int j = 0; j < TDIM; ++j) acc += cj[j] * We[o * TDIM + j];
        table[(size_t)k * DH + o] = acc;
    }
}

// ---------------------------------------------------------------------------
// Kernel 3: histogram of dst
// ---------------------------------------------------------------------------
__global__ __launch_bounds__(256) void hist_k(
    const int* __restrict__ ei, int* __restrict__ cnt, int E)
{
    int e = blockIdx.x * blockDim.x + threadIdx.x;
    if (e < E) atomicAdd(&cnt[ei[E + e]], 1);
}

// ---------------------------------------------------------------------------
// Scan: exclusive prefix sum over cnt[N] -> off[N]
// ---------------------------------------------------------------------------
__global__ __launch_bounds__(SCAN_T) void scan_reduce(
    const int* __restrict__ cnt, int* __restrict__ bsum, int N)
{
    __shared__ int sd[SCAN_T];
    int base = blockIdx.x * SCAN_B + threadIdx.x * SCAN_I;
    int s = 0;
#pragma unroll
    for (int k = 0; k < SCAN_I; ++k) { int i = base + k; if (i < N) s += cnt[i]; }
    sd[threadIdx.x] = s;
    __syncthreads();
    for (int st = SCAN_T / 2; st > 0; st >>= 1) {
        if (threadIdx.x < st) sd[threadIdx.x] += sd[threadIdx.x + st];
        __syncthreads();
    }
    if (threadIdx.x == 0) bsum[blockIdx.x] = sd[0];
}

__global__ __launch_bounds__(1024) void scan_bsum(int* __restrict__ bsum, int nb)
{
    __shared__ int sd[1024];
    int t = threadIdx.x;
    int orig = (t < nb) ? bsum[t] : 0;
    sd[t] = orig;
    __syncthreads();
    for (int st = 1; st < 1024; st <<= 1) {
        int v = (t >= st) ? sd[t - st] : 0;
        __syncthreads();
        sd[t] += v;
        __syncthreads();
    }
    if (t < nb) bsum[t] = sd[t] - orig;   // exclusive
}

__global__ __launch_bounds__(SCAN_T) void scan_final(
    const int* __restrict__ cnt, const int* __restrict__ bsum,
    int* __restrict__ off, int N)
{
    __shared__ int sd[SCAN_T];
    int t = threadIdx.x;
    int base = blockIdx.x * SCAN_B + t * SCAN_I;
    int loc[SCAN_I];
    int s = 0;
#pragma unroll
    for (int k = 0; k < SCAN_I; ++k) { int i = base + k; loc[k] = (i < N) ? cnt[i] : 0; s += loc[k]; }
    int orig = s;
    sd[t] = s;
    __syncthreads();
    for (int st = 1; st < SCAN_T; st <<= 1) {
        int v = (t >= st) ? sd[t - st] : 0;
        __syncthreads();
        sd[t] += v;
        __syncthreads();
    }
    int ex = sd[t] - orig + bsum[blockIdx.x];
#pragma unroll
    for (int k = 0; k < SCAN_I; ++k) {
        int i = base + k;
        if (i < N) { off[i] = ex; ex += loc[k]; }
    }
}

// ---------------------------------------------------------------------------
// init_aux: bcur[b] = bucket start offset; off[N] = E
// ---------------------------------------------------------------------------
__global__ void init_aux(int* __restrict__ off, int* __restrict__ bcur,
                         int N, int E, int NBK)
{
    int tid = threadIdx.x;
    if (tid < NBK) bcur[tid] = off[tid << NBSH];
    if (tid == 0) off[N] = E;
}

// ---------------------------------------------------------------------------
// S1: bucketed staging scatter. stg entry = {src | localdst<<17, rel bits}
// ---------------------------------------------------------------------------
__global__ __launch_bounds__(256) void s1_bucket(
    const int* __restrict__ ei, const float* __restrict__ t,
    const float* __restrict__ ntime,
    int* __restrict__ bcur, int2* __restrict__ stg, int E, int NBK)
{
    __shared__ int lcnt[128];
    __shared__ int lpos[128];
    int base = blockIdx.x * S1_TILE;
    if (threadIdx.x < 128) lcnt[threadIdx.x] = 0;
    __syncthreads();

    // phase A: per-bucket counts for this tile
#pragma unroll 4
    for (int i = 0; i < S1_TILE / 256; ++i) {
        int e = base + i * 256 + threadIdx.x;
        if (e < E) {
            int d = ei[E + e];
            atomicAdd(&lcnt[d >> NBSH], 1);
        }
    }
    __syncthreads();

    // reserve global runs
    if (threadIdx.x < NBK) {
        int c = lcnt[threadIdx.x];
        lpos[threadIdx.x] = (c > 0) ? atomicAdd(&bcur[threadIdx.x], c) : 0;
    }
    __syncthreads();

    // phase B: write staged entries
#pragma unroll 4
    for (int i = 0; i < S1_TILE / 256; ++i) {
        int e = base + i * 256 + threadIdx.x;
        if (e < E) {
            int d = ei[E + e];
            int s = ei[e];
            float rel = ntime[s] - t[e];
            int b = d >> NBSH;
            int pos = atomicAdd(&lpos[b], 1);
            stg[pos] = make_int2(s | ((d - (b << NBSH)) << 17), __float_as_int(rel));
        }
    }
}

// ---------------------------------------------------------------------------
// S2: within-bucket scatter to final CSR position (LDS node cursors)
// ---------------------------------------------------------------------------
__global__ __launch_bounds__(1024) void s2_scatter(
    const int* __restrict__ off, const int2* __restrict__ stg,
    int2* __restrict__ payload, int N)
{
    __shared__ int lcur[1 << NBSH];
    int nb0 = blockIdx.x << NBSH;
    int nodes = min(1 << NBSH, N - nb0);
    for (int i = threadIdx.x; i < nodes; i += blockDim.x)
        lcur[i] = off[nb0 + i];
    __syncthreads();

    int lo = off[nb0];
    int hi = off[min(nb0 + (1 << NBSH), N)];
    for (int i = lo + threadIdx.x; i < hi; i += blockDim.x) {
        int2 pl = stg[i];
        int ldst = ((unsigned int)pl.x) >> 17;
        int pos = atomicAdd(&lcur[ldst], 1);
        payload[pos] = make_int2(pl.x & 0x1FFFF, pl.y);
    }
}

// ---------------------------------------------------------------------------
// gather + finalize. 8 lanes per dst node, no atomics. kv in bf16.
// ---------------------------------------------------------------------------
__global__ __launch_bounds__(256) void gather_pass(
    const int* __restrict__ off, const int2* __restrict__ payload,
    const float* __restrict__ qn, const unsigned short* __restrict__ kvn,
    const float* __restrict__ skv, const float* __restrict__ table,
    const float* __restrict__ Wout, const float* __restrict__ bout,
    float* __restrict__ out, int N)
{
    int tid = blockIdx.x * blockDim.x + threadIdx.x;
    int d = tid >> 3;          // 8 lanes per dst
    int sub = tid & 7;         // channel group: 4 floats each
    if (d >= N) return;

    const float4 q = *(const float4*)(qn + (size_t)d * DH + sub * 4);
    float4 acc; acc.x = acc.y = acc.z = acc.w = 0.0f;
    float ssum = 0.0f;

    int beg = off[d];
    int end = off[d + 1];
    for (int j = beg; j < end; ++j) {
        int2 pl = payload[j];
        int src = pl.x;
        float rel = __int_as_float(pl.y);
        float u = (rel + 1.0f) * ((float)TABK * 0.5f);
        int i0 = (int)u;
        i0 = min(max(i0, 0), TABK - 1);
        float fr = u - (float)i0;

        const float4 t0 = *(const float4*)(table + (size_t)i0 * DH + sub * 4);
        const float4 t1 = *(const float4*)(table + (size_t)(i0 + 1) * DH + sub * 4);
        float4 ev;
        ev.x = t0.x + fr * (t1.x - t0.x);
        ev.y = t0.y + fr * (t1.y - t0.y);
        ev.z = t0.z + fr * (t1.z - t0.z);
        ev.w = t0.w + fr * (t1.w - t0.w);

        const unsigned short* row = kvn + (size_t)src * 64;
        uint2 kb = *(const uint2*)(row + sub * 4);
        uint2 vb = *(const uint2*)(row + 32 + sub * 4);

        float part = q.x * (bfl(kb.x) + ev.x) + q.y * (bfh(kb.x) + ev.y)
                   + q.z * (bfl(kb.y) + ev.z) + q.w * (bfh(kb.y) + ev.w);
        part += __shfl_xor(part, 1);
        part += __shfl_xor(part, 2);
        float wgt = __expf(part * 0.25f);   // 1/sqrt(C)=0.25; logits tiny, no max needed
        ssum += wgt;

        acc.x += (bfl(vb.x) + ev.x) * wgt;
        acc.y += (bfh(vb.x) + ev.y) * wgt;
        acc.z += (bfl(vb.y) + ev.z) * wgt;
        acc.w += (bfh(vb.y) + ev.w) * wgt;
    }

    float r = (ssum > 0.0f) ? 1.0f / ssum : 0.0f;
    const float4 sk = *(const float4*)(skv + (size_t)d * DH + sub * 4);
    float4 h;
    h.x = acc.x * r + sk.x;
    h.y = acc.y * r + sk.y;
    h.z = acc.z * r + sk.z;
    h.w = acc.w * r + sk.w;

    const float4 w0 = *(const float4*)(Wout + sub * 4);
    const float4 w1 = *(const float4*)(Wout + DH + sub * 4);
    float l0 = h.x * w0.x + h.y * w0.y + h.z * w0.z + h.w * w0.w;
    float l1 = h.x * w1.x + h.y * w1.y + h.z * w1.z + h.w * w1.w;
    l0 += __shfl_xor(l0, 1); l0 += __shfl_xor(l0, 2); l0 += __shfl_xor(l0, 4);
    l1 += __shfl_xor(l1, 1); l1 += __shfl_xor(l1, 2); l1 += __shfl_xor(l1, 4);

    if (sub == 0) {
        l0 += bout[0];
        l1 += bout[1];
        float m = fmaxf(l0, l1);
        float lse = m + logf(__expf(l0 - m) + __expf(l1 - m));
        float2 o; o.x = l0 - lse; o.y = l1 - lse;
        *(float2*)(out + (size_t)d * 2) = o;
    }
}

// ---------------------------------------------------------------------------
extern "C" void kernel_launch(void* const* d_in, const int* in_sizes, int n_in,
                              void* d_out, int out_size, void* d_ws, size_t ws_size,
                              hipStream_t stream)
{
    const float* x      = (const float*)d_in[0];
    const int*   ei     = (const int*)d_in[1];
    const float* t      = (const float*)d_in[2];
    const float* ntime  = (const float*)d_in[3];
    const float* freq   = (const float*)d_in[4];
    const float* phase  = (const float*)d_in[5];
    const float* Wl     = (const float*)d_in[6];
    const float* bl     = (const float*)d_in[7];
    const float* Wq     = (const float*)d_in[8];
    const float* bq     = (const float*)d_in[9];
    const float* Wk     = (const float*)d_in[10];
    const float* bk     = (const float*)d_in[11];
    const float* Wv     = (const float*)d_in[12];
    const float* bv     = (const float*)d_in[13];
    const float* We     = (const float*)d_in[14];
    const float* be     = (const float*)d_in[15];
    const float* Ws     = (const float*)d_in[16];
    const float* bs     = (const float*)d_in[17];
    const float* Wout   = (const float*)d_in[18];
    const float* bout   = (const float*)d_in[19];

    const int E = in_sizes[2];        // t has E elements
    const int N = in_sizes[3];        // node_time has N elements
    const int NBK = (N + (1 << NBSH) - 1) >> NBSH;   // <=128 for N<=131072

    char* wsb = (char*)d_ws;
    int2*  stg     = (int2*)wsb;            wsb += (size_t)E * sizeof(int2);
    int2*  payload = (int2*)wsb;            wsb += (size_t)E * sizeof(int2);
    float* qn   = (float*)wsb;              wsb += (size_t)N * DH * 4;
    unsigned short* kvn = (unsigned short*)wsb; wsb += (size_t)N * 64 * 2;
    float* skv  = (float*)wsb;              wsb += (size_t)N * DH * 4;
    float* tab  = (float*)wsb;              wsb += (size_t)(TABK + 1) * DH * 4;
    int*   cnt  = (int*)wsb;                wsb += (size_t)N * 4;
    int*   off  = (int*)wsb;                wsb += (size_t)(N + 1) * 4;
    int*   bsum = (int*)wsb;                wsb += 1024 * 4;
    int*   bcur = (int*)wsb;                wsb += 128 * 4;

    float* out = (float*)d_out;

    int nblk = (N + 255) / 256;
    int eblk = (E + 255) / 256;
    int sblk = (N + SCAN_B - 1) / SCAN_B;
    int s1blk = (E + S1_TILE - 1) / S1_TILE;

    node_prep<<<nblk, 256, 0, stream>>>(x, Wl, bl, Wq, bq, Wk, bk, Wv, bv, Ws, bs,
                                        qn, kvn, skv, cnt, N);
    build_table<<<(TABK + 64) / 64, 64, 0, stream>>>(We, be, freq, phase, tab);
    hist_k<<<eblk, 256, 0, stream>>>(ei, cnt, E);
    scan_reduce<<<sblk, SCAN_T, 0, stream>>>(cnt, bsum, N);
    scan_bsum<<<1, 1024, 0, stream>>>(bsum, sblk);
    scan_final<<<sblk, SCAN_T, 0, stream>>>(cnt, bsum, off, N);
    init_aux<<<1, 128, 0, stream>>>(off, bcur, N, E, NBK);
    s1_bucket<<<s1blk, 256, 0, stream>>>(ei, t, ntime, bcur, stg, E, NBK);
    s2_scatter<<<NBK, 1024, 0, stream>>>(off, stg, payload, N);

    int gblk = ((size_t)N * 8 + 255) / 256;
    gather_pass<<<gblk, 256, 0, stream>>>(off, payload, qn, kvn, skv,
                                          tab, Wout, bout, out, N);
}

// Round 4
// 309.386 us; speedup vs baseline: 18.6596x; 1.3326x over previous
//
#include <hip/hip_runtime.h>
#include <math.h>

// Problem constants (match reference)
#define D_IN 17
#define DH   32      // hidden dim = H*C
#define H    2
#define C    16
#define TDIM 32
#define TABK 2048    // time-encoding table resolution

#define NBSH 10                  // nodes per coarse bucket = 1024
#define S1_TILE 8192             // edges per s1 block
#define BC_TILE 4096             // edges per bcount block

// LDS weight pack offsets (floats) for node_prep
#define WL_OFF 0        // 32*17
#define BL_OFF 544
#define WQ_OFF 576      // 32*32
#define BQ_OFF 1600
#define WK_OFF 1632
#define BK_OFF 2656
#define WV_OFF 2688
#define BV_OFF 3712
#define WS_OFF 3744
#define BS_OFF 4768
#define WTOT   4800

__device__ __forceinline__ unsigned int f2bf(float x) {
    unsigned int u = __float_as_uint(x);
    return (u + 0x7fffu + ((u >> 16) & 1u)) >> 16;   // RTNE, no NaN expected
}
__device__ __forceinline__ float bfl(unsigned int u) { return __uint_as_float(u << 16); }
__device__ __forceinline__ float bfh(unsigned int u) { return __uint_as_float(u & 0xffff0000u); }

// ---------------------------------------------------------------------------
// Kernel 1: h1 = relu(x@Wl.T+bl); q (f32), k/v packed bf16 (128B/row), skip f32
//           block 0 also zeroes bcnt.
// ---------------------------------------------------------------------------
__global__ __launch_bounds__(256) void node_prep(
    const float* __restrict__ x,
    const float* __restrict__ Wl, const float* __restrict__ bl,
    const float* __restrict__ Wq, const float* __restrict__ bq,
    const float* __restrict__ Wk, const float* __restrict__ bk,
    const float* __restrict__ Wv, const float* __restrict__ bv,
    const float* __restrict__ Ws, const float* __restrict__ bs,
    float* __restrict__ qn, unsigned short* __restrict__ kvn,
    float* __restrict__ skv, int* __restrict__ bcnt, int N)
{
    if (blockIdx.x == 0 && threadIdx.x < 128) bcnt[threadIdx.x] = 0;

    __shared__ float w[WTOT];
    {
        const float* srcs[10] = {Wl, bl, Wq, bq, Wk, bk, Wv, bv, Ws, bs};
        const int   sizes[10] = {544, 32, 1024, 32, 1024, 32, 1024, 32, 1024, 32};
        int off = 0;
        for (int seg = 0; seg < 10; ++seg) {
            const float* p = srcs[seg];
            int sz = sizes[seg];
            for (int i = threadIdx.x; i < sz; i += blockDim.x) w[off + i] = p[i];
            off += sz;
        }
    }
    __syncthreads();

    int n = blockIdx.x * blockDim.x + threadIdx.x;
    if (n >= N) return;

    float xv[D_IN];
#pragma unroll
    for (int j = 0; j < D_IN; ++j) xv[j] = x[(size_t)n * D_IN + j];

    float h1[DH];
#pragma unroll
    for (int i = 0; i < DH; ++i) {
        float acc = w[BL_OFF + i];
#pragma unroll
        for (int j = 0; j < D_IN; ++j) acc += xv[j] * w[WL_OFF + i * D_IN + j];
        h1[i] = fmaxf(acc, 0.0f);
    }

    float outr[DH];

#define MATVEC(WO, BO)                                                       \
    {                                                                        \
        _Pragma("unroll")                                                    \
        for (int i = 0; i < DH; ++i) {                                       \
            float acc = w[(BO) + i];                                         \
            _Pragma("unroll")                                                \
            for (int c = 0; c < 8; ++c) {                                    \
                float4 wv = *(const float4*)&w[(WO) + i * DH + c * 4];       \
                acc += h1[c * 4 + 0] * wv.x + h1[c * 4 + 1] * wv.y           \
                     + h1[c * 4 + 2] * wv.z + h1[c * 4 + 3] * wv.w;          \
            }                                                                \
            outr[i] = acc;                                                   \
        }                                                                    \
    }

    // q -> f32
    MATVEC(WQ_OFF, BQ_OFF)
    {
        float4* dst4 = (float4*)(qn + (size_t)n * DH);
#pragma unroll
        for (int c = 0; c < 8; ++c) {
            float4 o; o.x = outr[c*4+0]; o.y = outr[c*4+1];
            o.z = outr[c*4+2]; o.w = outr[c*4+3];
            dst4[c] = o;
        }
    }

    // k -> bf16 packed (first 64B of row)
    unsigned int kw[16], vw[16];
    MATVEC(WK_OFF, BK_OFF)
#pragma unroll
    for (int i = 0; i < 16; ++i)
        kw[i] = f2bf(outr[2*i]) | (f2bf(outr[2*i+1]) << 16);

    // v -> bf16 packed (second 64B of row)
    MATVEC(WV_OFF, BV_OFF)
#pragma unroll
    for (int i = 0; i < 16; ++i)
        vw[i] = f2bf(outr[2*i]) | (f2bf(outr[2*i+1]) << 16);

    {
        uint4* row = (uint4*)(kvn + (size_t)n * 64);
#pragma unroll
        for (int c = 0; c < 4; ++c) {
            uint4 o; o.x = kw[c*4+0]; o.y = kw[c*4+1]; o.z = kw[c*4+2]; o.w = kw[c*4+3];
            row[c] = o;
        }
#pragma unroll
        for (int c = 0; c < 4; ++c) {
            uint4 o; o.x = vw[c*4+0]; o.y = vw[c*4+1]; o.z = vw[c*4+2]; o.w = vw[c*4+3];
            row[4 + c] = o;
        }
    }

    // skip -> f32
    MATVEC(WS_OFF, BS_OFF)
    {
        float4* dst4 = (float4*)(skv + (size_t)n * DH);
#pragma unroll
        for (int c = 0; c < 8; ++c) {
            float4 o; o.x = outr[c*4+0]; o.y = outr[c*4+1];
            o.z = outr[c*4+2]; o.w = outr[c*4+3];
            dst4[c] = o;
        }
    }
#undef MATVEC
}

// ---------------------------------------------------------------------------
// Kernel 2: time-encoding lookup table
// ---------------------------------------------------------------------------
__global__ __launch_bounds__(64) void build_table(
    const float* __restrict__ We, const float* __restrict__ be,
    const float* __restrict__ freq, const float* __restrict__ phase,
    float* __restrict__ table)
{
    int k = blockIdx.x * blockDim.x + threadIdx.x;
    if (k > TABK) return;
    float r = -1.0f + 2.0f * (float)k / (float)TABK;
    float cj[TDIM];
#pragma unroll
    for (int j = 0; j < TDIM; ++j) cj[j] = cosf(r * freq[j] + phase[j]);
#pragma unroll 4
    for (int o = 0; o < DH; ++o) {
        float acc = be[o];
#pragma unroll
        for (int j = 0; j < TDIM; ++j) acc += cj[j] * We[o * TDIM + j];
        table[(size_t)k * DH + o] = acc;
    }
}

// ---------------------------------------------------------------------------
// bcount: coarse-bucket histogram (LDS-aggregated; ~128 global atomics/block)
// ---------------------------------------------------------------------------
__global__ __launch_bounds__(256) void bcount_k(
    const int* __restrict__ ei, int* __restrict__ bcnt, int E, int NBK)
{
    __shared__ int lc[128];
    if (threadIdx.x < 128) lc[threadIdx.x] = 0;
    __syncthreads();
    int base = blockIdx.x * BC_TILE;
#pragma unroll 4
    for (int i = 0; i < BC_TILE / 256; ++i) {
        int e = base + i * 256 + threadIdx.x;
        if (e < E) atomicAdd(&lc[((unsigned int)ei[E + e]) >> NBSH], 1);
    }
    __syncthreads();
    if (threadIdx.x < NBK) {
        int c = lc[threadIdx.x];
        if (c) atomicAdd(&bcnt[threadIdx.x], c);
    }
}

// ---------------------------------------------------------------------------
// bscan: single block; exclusive scan of bcnt -> bstart, init bcur, off[N]=E
// ---------------------------------------------------------------------------
__global__ __launch_bounds__(128) void bscan_k(
    const int* __restrict__ bcnt, int* __restrict__ bstart,
    int* __restrict__ bcur, int* __restrict__ off, int N, int E, int NBK)
{
    __shared__ int sd[128];
    int t = threadIdx.x;
    int v0 = (t < NBK) ? bcnt[t] : 0;
    sd[t] = v0;
    __syncthreads();
    for (int st = 1; st < 128; st <<= 1) {
        int v = (t >= st) ? sd[t - st] : 0;
        __syncthreads();
        sd[t] += v;
        __syncthreads();
    }
    int ex = sd[t] - v0;
    if (t < NBK) { bstart[t] = ex; bcur[t] = ex; }
    if (t == 0)  { bstart[NBK] = E; off[N] = E; }
}

// ---------------------------------------------------------------------------
// S1: bucketed staging scatter. stg entry = {src | localdst<<17, rel bits}
// ---------------------------------------------------------------------------
__global__ __launch_bounds__(256) void s1_bucket(
    const int* __restrict__ ei, const float* __restrict__ t,
    const float* __restrict__ ntime,
    int* __restrict__ bcur, int2* __restrict__ stg, int E, int NBK)
{
    __shared__ int lcnt[128];
    __shared__ int lpos[128];
    int base = blockIdx.x * S1_TILE;
    if (threadIdx.x < 128) lcnt[threadIdx.x] = 0;
    __syncthreads();

    // phase A: per-bucket counts for this tile
#pragma unroll 4
    for (int i = 0; i < S1_TILE / 256; ++i) {
        int e = base + i * 256 + threadIdx.x;
        if (e < E) {
            int d = ei[E + e];
            atomicAdd(&lcnt[d >> NBSH], 1);
        }
    }
    __syncthreads();

    // reserve global runs
    if (threadIdx.x < NBK) {
        int c = lcnt[threadIdx.x];
        lpos[threadIdx.x] = (c > 0) ? atomicAdd(&bcur[threadIdx.x], c) : 0;
    }
    __syncthreads();

    // phase B: write staged entries
#pragma unroll 4
    for (int i = 0; i < S1_TILE / 256; ++i) {
        int e = base + i * 256 + threadIdx.x;
        if (e < E) {
            int d = ei[E + e];
            int s = ei[e];
            float rel = ntime[s] - t[e];
            int b = d >> NBSH;
            int pos = atomicAdd(&lpos[b], 1);
            stg[pos] = make_int2(s | ((d - (b << NBSH)) << 17), __float_as_int(rel));
        }
    }
}

// ---------------------------------------------------------------------------
// S2: per-bucket LDS histogram + scan -> off[]; scatter payload via LDS cursors
// ---------------------------------------------------------------------------
__global__ __launch_bounds__(1024) void s2_hist_scatter(
    const int* __restrict__ bstart, const int2* __restrict__ stg,
    int2* __restrict__ payload, int* __restrict__ off, int N)
{
    __shared__ int lcnt[1 << NBSH];
    int t = threadIdx.x;
    int nb0 = blockIdx.x << NBSH;
    lcnt[t] = 0;
    __syncthreads();

    int lo = bstart[blockIdx.x];
    int hi = bstart[blockIdx.x + 1];

    // pass 1: local histogram
    for (int i = lo + t; i < hi; i += 1024)
        atomicAdd(&lcnt[((unsigned int)stg[i].x) >> 17], 1);
    __syncthreads();

    // in-place Hillis-Steele inclusive scan
    int cntv = lcnt[t];
    for (int st = 1; st < 1024; st <<= 1) {
        int v = (t >= st) ? lcnt[t - st] : 0;
        __syncthreads();
        lcnt[t] += v;
        __syncthreads();
    }
    int gpos = lo + lcnt[t] - cntv;   // global CSR offset for node nb0+t
    if (nb0 + t < N) off[nb0 + t] = gpos;
    __syncthreads();
    lcnt[t] = gpos;                    // becomes the scatter cursor
    __syncthreads();

    // pass 2: scatter to final position (stg run is L2-hot)
    for (int i = lo + t; i < hi; i += 1024) {
        int2 pl = stg[i];
        int ld = ((unsigned int)pl.x) >> 17;
        int pos = atomicAdd(&lcnt[ld], 1);
        payload[pos] = make_int2(pl.x & 0x1FFFF, pl.y);
    }
}

// ---------------------------------------------------------------------------
// gather + finalize. 8 lanes per dst node, no atomics. kv in bf16.
// ---------------------------------------------------------------------------
__global__ __launch_bounds__(256) void gather_pass(
    const int* __restrict__ off, const int2* __restrict__ payload,
    const float* __restrict__ qn, const unsigned short* __restrict__ kvn,
    const float* __restrict__ skv, const float* __restrict__ table,
    const float* __restrict__ Wout, const float* __restrict__ bout,
    float* __restrict__ out, int N)
{
    int tid = blockIdx.x * blockDim.x + threadIdx.x;
    int d = tid >> 3;          // 8 lanes per dst
    int sub = tid & 7;         // channel group: 4 floats each
    if (d >= N) return;

    const float4 q = *(const float4*)(qn + (size_t)d * DH + sub * 4);
    float4 acc; acc.x = acc.y = acc.z = acc.w = 0.0f;
    float ssum = 0.0f;

    int beg = off[d];
    int end = off[d + 1];
    for (int j = beg; j < end; ++j) {
        int2 pl = payload[j];
        int src = pl.x;
        float rel = __int_as_float(pl.y);
        float u = (rel + 1.0f) * ((float)TABK * 0.5f);
        int i0 = (int)u;
        i0 = min(max(i0, 0), TABK - 1);
        float fr = u - (float)i0;

        const float4 t0 = *(const float4*)(table + (size_t)i0 * DH + sub * 4);
        const float4 t1 = *(const float4*)(table + (size_t)(i0 + 1) * DH + sub * 4);
        float4 ev;
        ev.x = t0.x + fr * (t1.x - t0.x);
        ev.y = t0.y + fr * (t1.y - t0.y);
        ev.z = t0.z + fr * (t1.z - t0.z);
        ev.w = t0.w + fr * (t1.w - t0.w);

        const unsigned short* row = kvn + (size_t)src * 64;
        uint2 kb = *(const uint2*)(row + sub * 4);
        uint2 vb = *(const uint2*)(row + 32 + sub * 4);

        float part = q.x * (bfl(kb.x) + ev.x) + q.y * (bfh(kb.x) + ev.y)
                   + q.z * (bfl(kb.y) + ev.z) + q.w * (bfh(kb.y) + ev.w);
        part += __shfl_xor(part, 1);
        part += __shfl_xor(part, 2);
        float wgt = __expf(part * 0.25f);   // 1/sqrt(C)=0.25; logits tiny, no max needed
        ssum += wgt;

        acc.x += (bfl(vb.x) + ev.x) * wgt;
        acc.y += (bfh(vb.x) + ev.y) * wgt;
        acc.z += (bfl(vb.y) + ev.z) * wgt;
        acc.w += (bfh(vb.y) + ev.w) * wgt;
    }

    float r = (ssum > 0.0f) ? 1.0f / ssum : 0.0f;
    const float4 sk = *(const float4*)(skv + (size_t)d * DH + sub * 4);
    float4 h;
    h.x = acc.x * r + sk.x;
    h.y = acc.y * r + sk.y;
    h.z = acc.z * r + sk.z;
    h.w = acc.w * r + sk.w;

    const float4 w0 = *(const float4*)(Wout + sub * 4);
    const float4 w1 = *(const float4*)(Wout + DH + sub * 4);
    float l0 = h.x * w0.x + h.y * w0.y + h.z * w0.z + h.w * w0.w;
    float l1 = h.x * w1.x + h.y * w1.y + h.z * w1.z + h.w * w1.w;
    l0 += __shfl_xor(l0, 1); l0 += __shfl_xor(l0, 2); l0 += __shfl_xor(l0, 4);
    l1 += __shfl_xor(l1, 1); l1 += __shfl_xor(l1, 2); l1 += __shfl_xor(l1, 4);

    if (sub == 0) {
        l0 += bout[0];
        l1 += bout[1];
        float m = fmaxf(l0, l1);
        float lse = m + logf(__expf(l0 - m) + __expf(l1 - m));
        float2 o; o.x = l0 - lse; o.y = l1 - lse;
        *(float2*)(out + (size_t)d * 2) = o;
    }
}

// ---------------------------------------------------------------------------
extern "C" void kernel_launch(void* const* d_in, const int* in_sizes, int n_in,
                              void* d_out, int out_size, void* d_ws, size_t ws_size,
                              hipStream_t stream)
{
    const float* x      = (const float*)d_in[0];
    const int*   ei     = (const int*)d_in[1];
    const float* t      = (const float*)d_in[2];
    const float* ntime  = (const float*)d_in[3];
    const float* freq   = (const float*)d_in[4];
    const float* phase  = (const float*)d_in[5];
    const float* Wl     = (const float*)d_in[6];
    const float* bl     = (const float*)d_in[7];
    const float* Wq     = (const float*)d_in[8];
    const float* bq     = (const float*)d_in[9];
    const float* Wk     = (const float*)d_in[10];
    const float* bk     = (const float*)d_in[11];
    const float* Wv     = (const float*)d_in[12];
    const float* bv     = (const float*)d_in[13];
    const float* We     = (const float*)d_in[14];
    const float* be     = (const float*)d_in[15];
    const float* Ws     = (const float*)d_in[16];
    const float* bs     = (const float*)d_in[17];
    const float* Wout   = (const float*)d_in[18];
    const float* bout   = (const float*)d_in[19];

    const int E = in_sizes[2];        // t has E elements
    const int N = in_sizes[3];        // node_time has N elements
    const int NBK = (N + (1 << NBSH) - 1) >> NBSH;   // <=128

    char* wsb = (char*)d_ws;
    int2*  stg     = (int2*)wsb;            wsb += (size_t)E * sizeof(int2);
    int2*  payload = (int2*)wsb;            wsb += (size_t)E * sizeof(int2);
    float* qn   = (float*)wsb;              wsb += (size_t)N * DH * 4;
    unsigned short* kvn = (unsigned short*)wsb; wsb += (size_t)N * 64 * 2;
    float* skv  = (float*)wsb;              wsb += (size_t)N * DH * 4;
    float* tab  = (float*)wsb;              wsb += (size_t)(TABK + 1) * DH * 4;
    int*   off  = (int*)wsb;                wsb += (size_t)(N + 1) * 4;
    int*   bcnt = (int*)wsb;                wsb += 128 * 4;
    int*   bstart = (int*)wsb;              wsb += 132 * 4;
    int*   bcur = (int*)wsb;                wsb += 128 * 4;

    float* out = (float*)d_out;

    int nblk = (N + 255) / 256;
    int s1blk = (E + S1_TILE - 1) / S1_TILE;
    int bcblk = (E + BC_TILE - 1) / BC_TILE;

    node_prep<<<nblk, 256, 0, stream>>>(x, Wl, bl, Wq, bq, Wk, bk, Wv, bv, Ws, bs,
                                        qn, kvn, skv, bcnt, N);
    build_table<<<(TABK + 64) / 64, 64, 0, stream>>>(We, be, freq, phase, tab);
    bcount_k<<<bcblk, 256, 0, stream>>>(ei, bcnt, E, NBK);
    bscan_k<<<1, 128, 0, stream>>>(bcnt, bstart, bcur, off, N, E, NBK);
    s1_bucket<<<s1blk, 256, 0, stream>>>(ei, t, ntime, bcur, stg, E, NBK);
    s2_hist_scatter<<<NBK, 1024, 0, stream>>>(bstart, stg, payload, off, N);

    int gblk = ((size_t)N * 8 + 255) / 256;
    gather_pass<<<gblk, 256, 0, stream>>>(off, payload, qn, kvn, skv,
                                          tab, Wout, bout, out, N);
}